// Round 1
// baseline (814.934 us; speedup 1.0000x reference)
//
#include <hip/hip_runtime.h>

// Problem shapes (fixed by reference setup_inputs):
constexpr int Bc = 8, Hc = 384, Wc = 1280, Cc = 8;

// Output tiling: each workgroup owns a 32x32 output tile and gathers all
// source pixels whose bilinear splat can reach it (|flo| <= 9 covered;
// P(|N(0,1)|>9) ~ 1e-19 -> no dropped taps in practice).
constexpr int TH = 32, TW = 32;
constexpr int HALO = 10;
constexpr int RH = TH + 2 * HALO;         // 52
constexpr int RW = TW + 2 * HALO;         // 52
constexpr int NSRC = RH * RW;             // 2704 sources per tile
constexpr int TILES_X = Wc / TW;          // 40
constexpr int TILES_Y = Hc / TH;          // 12
constexpr int NPIX = TH * TW;             // 1024
constexpr int BLK = 512;                  // 8 waves/block; 32KB LDS -> 4 blocks/CU

// Hardware LDS fp32 atomic add, fire-and-forget. HIP's atomicAdd(float*) on
// LDS lowers to a ds_read/ds_cmpst CAS retry loop (denormal-safety), which
// serializes at ~120cy/attempt per lane -- the measured 655us @ 5% VALUBusy.
// One base address + 16-bit offset immediates covers all 8 channels
// (channel stride = NPIX*4 = 4096 B, max 7*4096 = 28672 < 65536).
__device__ __forceinline__ void lds_fadd8(float* p, float4 ua, float4 ub, float wgt)
{
    auto* lp = (__attribute__((address_space(3))) float*)p;   // 32-bit LDS addr
    unsigned ad = (unsigned)(unsigned long long)lp;
    asm volatile(
        "ds_add_f32 %0, %1\n"
        "ds_add_f32 %0, %2 offset:4096\n"
        "ds_add_f32 %0, %3 offset:8192\n"
        "ds_add_f32 %0, %4 offset:12288\n"
        "ds_add_f32 %0, %5 offset:16384\n"
        "ds_add_f32 %0, %6 offset:20480\n"
        "ds_add_f32 %0, %7 offset:24576\n"
        "ds_add_f32 %0, %8 offset:28672\n"
        :
        : "v"(ad),
          "v"(ua.x * wgt), "v"(ua.y * wgt), "v"(ua.z * wgt), "v"(ua.w * wgt),
          "v"(ub.x * wgt), "v"(ub.y * wgt), "v"(ub.z * wgt), "v"(ub.w * wgt)
        : "memory");
}

__global__ __launch_bounds__(BLK) void fwd_warp_tile(
    const float* __restrict__ U, const float* __restrict__ flo,
    float* __restrict__ out)
{
    // channel-major accumulator: acc[c*NPIX + pix] -> consecutive lanes hit
    // consecutive banks (2-way alias = free on 64-lane wave)
    __shared__ float acc[Cc * NPIX];      // 32 KB

    int tile = blockIdx.x;
    int b   = tile / (TILES_X * TILES_Y);
    int r   = tile % (TILES_X * TILES_Y);
    int Y0 = (r / TILES_X) * TH;
    int X0 = (r % TILES_X) * TW;
    int t  = threadIdx.x;

    float4 z = {0.f, 0.f, 0.f, 0.f};
    #pragma unroll
    for (int i = 0; i < (Cc * NPIX / 4) / BLK; ++i)   // 4 iters
        reinterpret_cast<float4*>(acc)[i * BLK + t] = z;
    __syncthreads();

    const float half_w = (Wc - 1) * 0.5f;  // 639.5
    const float half_h = (Hc - 1) * 0.5f;  // 191.5
    const float2* flo2 = reinterpret_cast<const float2*>(flo);
    const float4* u4   = reinterpret_cast<const float4*>(U);

    // branch-free source decode with clamped load address
    auto src_of = [&](int i, int& h, int& w, bool& valid, int& sidx) {
        int sr = i / RW, sc = i - sr * RW;
        h = Y0 - HALO + sr;
        w = X0 - HALO + sc;
        valid = ((unsigned)h < (unsigned)Hc) & ((unsigned)w < (unsigned)Wc);
        int hc = min(max(h, 0), Hc - 1);
        int wc = min(max(w, 0), Wc - 1);
        sidx = (b * Hc + hc) * Wc + wc;
    };

    // ---- software pipeline: prefetch depth 1 ----
    int h, w, sidx; bool valid;
    src_of(min(t, NSRC - 1), h, w, valid, sidx);
    if (t >= NSRC) valid = false;
    float2 f  = flo2[sidx];
    float4 ua = u4[(size_t)sidx * 2];
    float4 ub = u4[(size_t)sidx * 2 + 1];

    for (int i = t; i < NSRC; i += BLK) {
        // issue next iteration's loads before touching current data
        int inext = i + BLK;
        int hn, wn, sn; bool vn;
        src_of(min(inext, NSRC - 1), hn, wn, vn, sn);
        if (inext >= NSRC) vn = false;
        float2 fn  = flo2[sn];
        float4 uan = u4[(size_t)sn * 2];
        float4 ubn = u4[(size_t)sn * 2 + 1];

        // process current source
        if (valid) {
            float xs = -1.0f + (float)w * (2.0f / (Wc - 1));
            float ys = -1.0f + (float)h * (2.0f / (Hc - 1));
            float x = (xs + f.x / half_w + 1.0f) * half_w;
            float y = (ys + f.y / half_h + 1.0f) * half_h;

            float x0f = floorf(x), y0f = floorf(y);
            int x0 = (int)x0f, y0 = (int)y0f;

            float wx[2] = { (x0f + 1.0f) - x, x - x0f };
            float wy[2] = { (y0f + 1.0f) - y, y - y0f };
            int   lx[2] = { x0 - X0, x0 + 1 - X0 };
            int   ly[2] = { y0 - Y0, y0 + 1 - Y0 };

            #pragma unroll
            for (int j = 0; j < 2; ++j) {
                #pragma unroll
                for (int k = 0; k < 2; ++k) {
                    if ((unsigned)lx[k] < (unsigned)TW &&
                        (unsigned)ly[j] < (unsigned)TH) {
                        float wgt = wx[k] * wy[j];
                        if (wgt != 0.0f) {
                            int pix = ly[j] * TW + lx[k];
                            lds_fadd8(&acc[pix], ua, ub, wgt);
                        }
                    }
                }
            }
        }
        // rotate pipeline registers
        h = hn; w = wn; valid = vn; f = fn; ua = uan; ub = ubn;
    }
    __syncthreads();

    // write out the tile: 1024 pixels x 2 float4, coalesced plain stores
    #pragma unroll
    for (int i = t; i < NPIX * 2; i += BLK) {
        int pix = i >> 1;
        int hf  = i & 1;
        int py = pix / TW, px = pix - py * TW;
        float4 v;
        v.x = acc[(hf * 4 + 0) * NPIX + pix];
        v.y = acc[(hf * 4 + 1) * NPIX + pix];
        v.z = acc[(hf * 4 + 2) * NPIX + pix];
        v.w = acc[(hf * 4 + 3) * NPIX + pix];
        size_t opix = (size_t)(b * Hc + Y0 + py) * Wc + (X0 + px);
        reinterpret_cast<float4*>(out)[opix * 2 + hf] = v;
    }
}

extern "C" void kernel_launch(void* const* d_in, const int* in_sizes, int n_in,
                              void* d_out, int out_size, void* d_ws, size_t ws_size,
                              hipStream_t stream)
{
    const float* U   = (const float*)d_in[0];
    const float* flo = (const float*)d_in[1];
    float* out = (float*)d_out;

    int grid = Bc * TILES_X * TILES_Y;   // 3840 tiles
    fwd_warp_tile<<<grid, BLK, 0, stream>>>(U, flo, out);
}

// Round 2
// 812.424 us; speedup vs baseline: 1.0031x; 1.0031x over previous
//
#include <hip/hip_runtime.h>

// Problem shapes (fixed by reference setup_inputs):
constexpr int Bc = 8, Hc = 384, Wc = 1280, Cc = 8;

// Output tiling: each workgroup owns a 32x32 output tile and gathers all
// source pixels whose bilinear splat can reach it (|flo| <= 9 covered;
// P(|N(0,1)|>9) ~ 1e-19 -> no dropped taps in practice).
constexpr int TH = 32, TW = 32;
constexpr int HALO = 10;
constexpr int RH = TH + 2 * HALO;         // 52
constexpr int RW = TW + 2 * HALO;         // 52
constexpr int NSRC = RH * RW;             // 2704 sources per tile
constexpr int TILES_X = Wc / TW;          // 40
constexpr int TILES_Y = Hc / TH;          // 12
constexpr int NPIX = TH * TW;             // 1024
constexpr int BLK = 512;
constexpr int NITER = (NSRC + BLK - 1) / BLK;   // 6 slots per thread

// Hardware LDS fp32 atomic add, fire-and-forget (proven correct in prev round).
// One base address + 16-bit offset immediates covers all 8 channels
// (channel stride = NPIX*4 = 4096 B, max 7*4096 = 28672 < 65536).
__device__ __forceinline__ void lds_fadd8(float* p, float4 ua, float4 ub, float wgt)
{
    auto* lp = (__attribute__((address_space(3))) float*)p;   // 32-bit LDS addr
    unsigned ad = (unsigned)(unsigned long long)lp;
    asm volatile(
        "ds_add_f32 %0, %1\n"
        "ds_add_f32 %0, %2 offset:4096\n"
        "ds_add_f32 %0, %3 offset:8192\n"
        "ds_add_f32 %0, %4 offset:12288\n"
        "ds_add_f32 %0, %5 offset:16384\n"
        "ds_add_f32 %0, %6 offset:20480\n"
        "ds_add_f32 %0, %7 offset:24576\n"
        "ds_add_f32 %0, %8 offset:28672\n"
        :
        : "v"(ad),
          "v"(ua.x * wgt), "v"(ua.y * wgt), "v"(ua.z * wgt), "v"(ua.w * wgt),
          "v"(ub.x * wgt), "v"(ub.y * wgt), "v"(ub.z * wgt), "v"(ub.w * wgt)
        : "memory");
}

// __launch_bounds__(512, 2): allow up to 256 VGPRs so the compiler does NOT
// register-minimize to 24 VGPRs (prev rounds) and destroy the load batching.
// ~2 blocks/CU resident; each wave carries 18 outstanding global loads.
__global__ __launch_bounds__(BLK, 2) void fwd_warp_tile(
    const float* __restrict__ U, const float* __restrict__ flo,
    float* __restrict__ out)
{
    // channel-major accumulator: acc[c*NPIX + pix]
    __shared__ float acc[Cc * NPIX];      // 32 KB

    int tile = blockIdx.x;
    int b   = tile / (TILES_X * TILES_Y);
    int r   = tile % (TILES_X * TILES_Y);
    int Y0 = (r / TILES_X) * TH;
    int X0 = (r % TILES_X) * TW;
    int t  = threadIdx.x;

    const float2* flo2 = reinterpret_cast<const float2*>(flo);
    const float4* u4   = reinterpret_cast<const float4*>(U);

    // branch-free source decode with clamped load address
    auto src_of = [&](int i, int& h, int& w, bool& valid, int& sidx) {
        int sr = i / RW, sc = i - sr * RW;
        h = Y0 - HALO + sr;
        w = X0 - HALO + sc;
        valid = ((unsigned)h < (unsigned)Hc) & ((unsigned)w < (unsigned)Wc);
        int hc = min(max(h, 0), Hc - 1);
        int wc = min(max(w, 0), Wc - 1);
        sidx = (b * Hc + hc) * Wc + wc;
    };

    // ---- phase 0: issue ALL loads for this thread's 6 source slots ----
    float2 f[NITER];
    float4 ua[NITER], ub[NITER];
    #pragma unroll
    for (int s = 0; s < NITER; ++s) {
        int i = min(t + s * BLK, NSRC - 1);
        int h, w, sidx; bool v;
        src_of(i, h, w, v, sidx);
        f[s]  = flo2[sidx];
        ua[s] = u4[(size_t)sidx * 2];
        ub[s] = u4[(size_t)sidx * 2 + 1];
    }
    // pin: loads stay issued here; latency hides under init + barrier drain
    __builtin_amdgcn_sched_barrier(0);

    // ---- phase 1: zero LDS accumulator while loads are in flight ----
    float4 z = {0.f, 0.f, 0.f, 0.f};
    #pragma unroll
    for (int i = 0; i < (Cc * NPIX / 4) / BLK; ++i)   // 4 iters
        reinterpret_cast<float4*>(acc)[i * BLK + t] = z;
    __syncthreads();

    // ---- phase 2: splat (register data only; no global accesses) ----
    #pragma unroll
    for (int s = 0; s < NITER; ++s) {
        int i = t + s * BLK;
        int h, w, sidx; bool valid;
        src_of(min(i, NSRC - 1), h, w, valid, sidx);
        if (i >= NSRC) valid = false;
        if (valid) {
            // exact algebraic fold of the reference grid math:
            // x = (x_s + f.x/half_w + 1)*half_w == w + f.x  (linspace identity)
            float x = (float)w + f[s].x;
            float y = (float)h + f[s].y;

            float x0f = floorf(x), y0f = floorf(y);
            int x0 = (int)x0f, y0 = (int)y0f;

            float wx[2] = { (x0f + 1.0f) - x, x - x0f };
            float wy[2] = { (y0f + 1.0f) - y, y - y0f };
            int   lx[2] = { x0 - X0, x0 + 1 - X0 };
            int   ly[2] = { y0 - Y0, y0 + 1 - Y0 };

            #pragma unroll
            for (int j = 0; j < 2; ++j) {
                #pragma unroll
                for (int k = 0; k < 2; ++k) {
                    if ((unsigned)lx[k] < (unsigned)TW &&
                        (unsigned)ly[j] < (unsigned)TH) {
                        float wgt = wx[k] * wy[j];
                        if (wgt != 0.0f) {
                            int pix = ly[j] * TW + lx[k];
                            lds_fadd8(&acc[pix], ua[s], ub[s], wgt);
                        }
                    }
                }
            }
        }
    }
    __syncthreads();

    // ---- epilogue: 1024 pixels x 2 float4, coalesced stores ----
    #pragma unroll
    for (int i = t; i < NPIX * 2; i += BLK) {
        int pix = i >> 1;
        int hf  = i & 1;
        int py = pix / TW, px = pix - py * TW;
        float4 v;
        v.x = acc[(hf * 4 + 0) * NPIX + pix];
        v.y = acc[(hf * 4 + 1) * NPIX + pix];
        v.z = acc[(hf * 4 + 2) * NPIX + pix];
        v.w = acc[(hf * 4 + 3) * NPIX + pix];
        size_t opix = (size_t)(b * Hc + Y0 + py) * Wc + (X0 + px);
        reinterpret_cast<float4*>(out)[opix * 2 + hf] = v;
    }
}

extern "C" void kernel_launch(void* const* d_in, const int* in_sizes, int n_in,
                              void* d_out, int out_size, void* d_ws, size_t ws_size,
                              hipStream_t stream)
{
    const float* U   = (const float*)d_in[0];
    const float* flo = (const float*)d_in[1];
    float* out = (float*)d_out;

    int grid = Bc * TILES_X * TILES_Y;   // 3840 tiles
    fwd_warp_tile<<<grid, BLK, 0, stream>>>(U, flo, out);
}

// Round 3
// 395.510 us; speedup vs baseline: 2.0605x; 2.0541x over previous
//
#include <hip/hip_runtime.h>
#include <math.h>

// Problem shapes (fixed by reference setup_inputs):
constexpr int Bc = 8, Hc = 384, Wc = 1280, Cc = 8;

// ---------------- gather kernel ----------------
// One thread per OUTPUT pixel. A source (h,w) contributes to pixel (py,px)
// iff |w+fx-px| <= 1 and |h+fy-py| <= 1. With |f|<=4.5, contributing sources
// lie within +-5 of the pixel -> 11x11 scan window. Sources with |f|>4.5
// (P ~ 6.8e-6 per component; ~50 expected in the whole tensor) are handled by
// a second scatter kernel with global atomics, stream-ordered after this one.
constexpr int TH = 16, TW = 16;              // output tile per block (256 thr)
constexpr int WIN = 5;                        // window half-width
constexpr float FMAX = 4.5f;                  // flow split threshold (exact fp32 cmp in BOTH kernels)
constexpr int RH = TH + 2 * WIN;              // 26
constexpr int RW = TW + 2 * WIN;              // 26
constexpr int NSRC = RH * RW;                 // 676 staged sources / tile
constexpr int TILES_X = Wc / TW;              // 80
constexpr int TILES_Y = Hc / TH;              // 24
constexpr int BLK = 256;

__global__ __launch_bounds__(BLK) void fwd_warp_gather(
    const float* __restrict__ U, const float* __restrict__ flo,
    float* __restrict__ out)
{
    // absolute splat coordinates (x,y) = (w+fx, h+fy) per source;
    // sentinel -1e9 for out-of-image or outlier sources (never hits).
    __shared__ float2 sxy[NSRC];              // 5.4 KB

    int tile = blockIdx.x;
    int b  = tile / (TILES_X * TILES_Y);
    int r  = tile % (TILES_X * TILES_Y);
    int Y0 = (r / TILES_X) * TH;
    int X0 = (r % TILES_X) * TW;
    int t  = threadIdx.x;

    const float2* flo2 = reinterpret_cast<const float2*>(flo);
    const float4* u4   = reinterpret_cast<const float4*>(U);

    // ---- stage splat coords (coalesced float2 reads) ----
    for (int i = t; i < NSRC; i += BLK) {
        int sy = i / RW, sx = i - sy * RW;
        int h = Y0 - WIN + sy;
        int w = X0 - WIN + sx;
        float2 v = make_float2(-1e9f, -1e9f);
        if ((unsigned)h < (unsigned)Hc && (unsigned)w < (unsigned)Wc) {
            float2 f = flo2[(b * Hc + h) * Wc + w];
            if (fabsf(f.x) <= FMAX && fabsf(f.y) <= FMAX)
                v = make_float2((float)w + f.x, (float)h + f.y);
        }
        sxy[i] = v;
    }
    __syncthreads();

    // ---- per-pixel gather ----
    int lpy = t / TW, lpx = t - (t / TW) * TW;
    int py = Y0 + lpy, px = X0 + lpx;
    float pxf = (float)px, pyf = (float)py;
    int pixbase = (b * Hc + py) * Wc + px;    // my pixel's flat index

    float a0 = 0.f, a1 = 0.f, a2 = 0.f, a3 = 0.f;
    float a4 = 0.f, a5 = 0.f, a6 = 0.f, a7 = 0.f;

    for (int dy = 0; dy < 2 * WIN + 1; ++dy) {
        int rowb   = (lpy + dy) * RW + lpx;   // LDS row base for this pixel
        int rowsrc = pixbase + (dy - WIN) * Wc;
        #pragma unroll
        for (int dx = 0; dx < 2 * WIN + 1; ++dx) {
            float2 s = sxy[rowb + dx];
            float fdx = s.x - pxf;
            float fdy = s.y - pyf;
            // strict < 1: boundary taps have exactly-zero weight (reference
            // skips wgt==0 adds -> identical). Sentinel sources never pass.
            if (fmaxf(fabsf(fdx), fabsf(fdy)) < 1.0f) {
                float wgt = (1.0f - fabsf(fdx)) * (1.0f - fabsf(fdy));
                int sidx = rowsrc + (dx - WIN);
                float4 ua = u4[(size_t)sidx * 2];
                float4 ub = u4[(size_t)sidx * 2 + 1];
                a0 += ua.x * wgt; a1 += ua.y * wgt;
                a2 += ua.z * wgt; a3 += ua.w * wgt;
                a4 += ub.x * wgt; a5 += ub.y * wgt;
                a6 += ub.z * wgt; a7 += ub.w * wgt;
            }
        }
    }

    // plain coalesced stores (no atomics): full overwrite of my pixel
    float4 o0 = {a0, a1, a2, a3};
    float4 o1 = {a4, a5, a6, a7};
    reinterpret_cast<float4*>(out)[(size_t)pixbase * 2]     = o0;
    reinterpret_cast<float4*>(out)[(size_t)pixbase * 2 + 1] = o1;
}

// ---------------- outlier scatter kernel ----------------
// Handles the ~50 sources with |f|>4.5 exactly like the reference (clamp +
// zero-weight logic), adding into 'out' with global atomics AFTER the gather
// kernel has fully written it (same stream -> ordered). Perf-irrelevant.
__global__ __launch_bounds__(BLK) void fwd_warp_outlier(
    const float* __restrict__ U, const float* __restrict__ flo,
    float* __restrict__ out)
{
    int tid = blockIdx.x * BLK + threadIdx.x;
    int total = Bc * Hc * Wc;
    if (tid >= total) return;
    float2 f = reinterpret_cast<const float2*>(flo)[tid];
    if (fabsf(f.x) <= FMAX && fabsf(f.y) <= FMAX) return;   // bit-identical predicate

    int w = tid % Wc;
    int h = (tid / Wc) % Hc;
    float x = (float)w + f.x;
    float y = (float)h + f.y;
    float x0f = floorf(x), y0f = floorf(y);
    int x0 = (int)x0f, y0 = (int)y0f;
    float wx[2] = { (x0f + 1.0f) - x, x - x0f };
    float wy[2] = { (y0f + 1.0f) - y, y - y0f };

    const float4* u4 = reinterpret_cast<const float4*>(U);
    float4 ua = u4[(size_t)tid * 2];
    float4 ub = u4[(size_t)tid * 2 + 1];
    int bbase = tid - (h * Wc + w);           // b*Hc*Wc

    #pragma unroll
    for (int j = 0; j < 2; ++j) {
        #pragma unroll
        for (int k = 0; k < 2; ++k) {
            int ty = y0 + j, tx = x0 + k;
            if ((unsigned)ty < (unsigned)Hc && (unsigned)tx < (unsigned)Wc) {
                float wgt = wx[k] * wy[j];
                if (wgt != 0.0f) {
                    float* p = out + ((size_t)(bbase + ty * Wc + tx)) * 8;
                    atomicAdd(p + 0, ua.x * wgt);
                    atomicAdd(p + 1, ua.y * wgt);
                    atomicAdd(p + 2, ua.z * wgt);
                    atomicAdd(p + 3, ua.w * wgt);
                    atomicAdd(p + 4, ub.x * wgt);
                    atomicAdd(p + 5, ub.y * wgt);
                    atomicAdd(p + 6, ub.z * wgt);
                    atomicAdd(p + 7, ub.w * wgt);
                }
            }
        }
    }
}

extern "C" void kernel_launch(void* const* d_in, const int* in_sizes, int n_in,
                              void* d_out, int out_size, void* d_ws, size_t ws_size,
                              hipStream_t stream)
{
    const float* U   = (const float*)d_in[0];
    const float* flo = (const float*)d_in[1];
    float* out = (float*)d_out;

    int grid_g = Bc * TILES_X * TILES_Y;            // 15360 tiles
    fwd_warp_gather<<<grid_g, BLK, 0, stream>>>(U, flo, out);

    int grid_o = (Bc * Hc * Wc + BLK - 1) / BLK;    // 15360 blocks
    fwd_warp_outlier<<<grid_o, BLK, 0, stream>>>(U, flo, out);
}